// Round 1
// baseline (3523.615 us; speedup 1.0000x reference)
//
#include <hip/hip_runtime.h>

#define NNODES 100000
#define NEDGES 600000
#define NGRAPH 64
#define HID 128
#define RHD 500

__device__ __forceinline__ float leaky1(float x) { return x >= 0.0f ? x : 0.01f * x; }

// ---------------- layer 0: edge message (d=2) ----------------
__global__ __launch_bounds__(256) void edge0_kernel(
    const float* __restrict__ x, const int* __restrict__ ei,
    const float* __restrict__ ea, const float* __restrict__ ew,
    const float* __restrict__ eb, float* __restrict__ aggr)
{
    int e = blockIdx.x * 256 + threadIdx.x;
    if (e >= NEDGES) return;
    int s = ei[e];
    int d = ei[NEDGES + e];
    float a[7];
#pragma unroll
    for (int k = 0; k < 7; ++k) a[k] = ea[e * 7 + k];
    float e0 = eb[0], e1 = eb[1];
#pragma unroll
    for (int k = 0; k < 7; ++k) { e0 = fmaf(a[k], ew[k], e0); e1 = fmaf(a[k], ew[7 + k], e1); }
    float m0 = fmaxf(x[s * 2 + 0] + e0, 0.0f);
    float m1 = fmaxf(x[s * 2 + 1] + e1, 0.0f);
    atomicAdd(&aggr[d * 2 + 0], m0);
    atomicAdd(&aggr[d * 2 + 1], m1);
}

// ---------------- hidden layers: edge message (d=128), one wave per edge ----------------
__global__ __launch_bounds__(256) void edge_kernel(
    const float* __restrict__ xin, const int* __restrict__ ei,
    const float* __restrict__ ea, const float* __restrict__ ew,
    const float* __restrict__ eb, float* __restrict__ aggr)
{
    int lane = threadIdx.x & 63;
    int e = blockIdx.x * 4 + (threadIdx.x >> 6);
    int s = ei[e];
    int d = ei[NEDGES + e];
    float a[7];
#pragma unroll
    for (int k = 0; k < 7; ++k) a[k] = ea[e * 7 + k];
    int j0 = lane, j1 = lane + 64;
    float acc0 = eb[j0], acc1 = eb[j1];
#pragma unroll
    for (int k = 0; k < 7; ++k) {
        acc0 = fmaf(a[k], ew[j0 * 7 + k], acc0);
        acc1 = fmaf(a[k], ew[j1 * 7 + k], acc1);
    }
    float m0 = fmaxf(xin[s * HID + j0] + acc0, 0.0f);
    float m1 = fmaxf(xin[s * HID + j1] + acc1, 0.0f);
    atomicAdd(&aggr[d * HID + j0], m0);
    atomicAdd(&aggr[d * HID + j1], m1);
}

// ---------------- layer 0: GEMM1 (in=2 -> 128) ----------------
__global__ __launch_bounds__(256) void gemm1_l0_kernel(
    const float* __restrict__ x, const float* __restrict__ aggr,
    const float* __restrict__ w1, const float* __restrict__ b1,
    float* __restrict__ h1)
{
    int n = blockIdx.x * 256 + threadIdx.x;
    if (n >= NNODES) return;
    float x0 = x[n * 2 + 0] + aggr[n * 2 + 0];
    float x1 = x[n * 2 + 1] + aggr[n * 2 + 1];
    float4* out4 = (float4*)(h1 + (size_t)n * HID);
    for (int j = 0; j < HID; j += 4) {
        float4 o;
        o.x = fmaf(x1, w1[(j + 0) * 2 + 1], fmaf(x0, w1[(j + 0) * 2 + 0], b1[j + 0]));
        o.y = fmaf(x1, w1[(j + 1) * 2 + 1], fmaf(x0, w1[(j + 1) * 2 + 0], b1[j + 1]));
        o.z = fmaf(x1, w1[(j + 2) * 2 + 1], fmaf(x0, w1[(j + 2) * 2 + 0], b1[j + 2]));
        o.w = fmaf(x1, w1[(j + 3) * 2 + 1], fmaf(x0, w1[(j + 3) * 2 + 0], b1[j + 3]));
        out4[j >> 2] = o;
    }
}

// ---------------- hidden layers: GEMM1 h1 = (x+aggr) @ W1^T + b1 ----------------
__global__ __launch_bounds__(256) void gemm1_kernel(
    const float* __restrict__ xin, const float* __restrict__ aggr,
    const float* __restrict__ w1, const float* __restrict__ b1,
    float* __restrict__ h1)
{
    int n = blockIdx.x * 256 + threadIdx.x;
    if (n >= NNODES) return;
    const float4* xi4 = (const float4*)(xin + (size_t)n * HID);
    const float4* ag4 = (const float4*)(aggr + (size_t)n * HID);
    float4 hrow[32];
#pragma unroll
    for (int k = 0; k < 32; ++k) {
        float4 a = xi4[k], b = ag4[k];
        hrow[k] = make_float4(a.x + b.x, a.y + b.y, a.z + b.z, a.w + b.w);
    }
    const float4* w4 = (const float4*)w1;
    float4* out4 = (float4*)(h1 + (size_t)n * HID);
    for (int j = 0; j < HID; j += 4) {
        const float4* w0p = w4 + (size_t)(j + 0) * 32;
        const float4* w1p = w4 + (size_t)(j + 1) * 32;
        const float4* w2p = w4 + (size_t)(j + 2) * 32;
        const float4* w3p = w4 + (size_t)(j + 3) * 32;
        float a0 = b1[j + 0], a1 = b1[j + 1], a2 = b1[j + 2], a3 = b1[j + 3];
#pragma unroll
        for (int k = 0; k < 32; ++k) {
            float4 h4 = hrow[k];
            float4 q0 = w0p[k], q1 = w1p[k], q2 = w2p[k], q3 = w3p[k];
            a0 = fmaf(h4.x, q0.x, a0); a0 = fmaf(h4.y, q0.y, a0); a0 = fmaf(h4.z, q0.z, a0); a0 = fmaf(h4.w, q0.w, a0);
            a1 = fmaf(h4.x, q1.x, a1); a1 = fmaf(h4.y, q1.y, a1); a1 = fmaf(h4.z, q1.z, a1); a1 = fmaf(h4.w, q1.w, a1);
            a2 = fmaf(h4.x, q2.x, a2); a2 = fmaf(h4.y, q2.y, a2); a2 = fmaf(h4.z, q2.z, a2); a2 = fmaf(h4.w, q2.w, a2);
            a3 = fmaf(h4.x, q3.x, a3); a3 = fmaf(h4.y, q3.y, a3); a3 = fmaf(h4.z, q3.z, a3); a3 = fmaf(h4.w, q3.w, a3);
        }
        out4[j >> 2] = make_float4(a0, a1, a2, a3);
    }
}

// ---------------- BN statistics: per-channel sum and sumsq over all nodes ----------------
__global__ __launch_bounds__(256) void bn_stats_kernel(
    const float* __restrict__ h1, float* __restrict__ acc)
{
    __shared__ float ls[HID], lq[HID];
    int c = threadIdx.x & 127;
    int half = threadIdx.x >> 7;
    int base = blockIdx.x * 256;
    int end = base + 256; if (end > NNODES) end = NNODES;
    float s = 0.0f, q = 0.0f;
    for (int r = base + half; r < end; r += 2) {
        float v = h1[(size_t)r * HID + c];
        s += v;
        q = fmaf(v, v, q);
    }
    if (half) { ls[c] = s; lq[c] = q; }
    __syncthreads();
    if (!half) {
        s += ls[c]; q += lq[c];
        atomicAdd(&acc[c], s);
        atomicAdd(&acc[HID + c], q);
    }
}

// ---------------- GEMM2: BN -> leaky -> @W2^T + b2 -> leaky -> leaky; optionally zero aggr ----------------
__global__ __launch_bounds__(256) void gemm2_kernel(
    const float* __restrict__ h1, const float* __restrict__ bnacc,
    const float* __restrict__ gamma, const float* __restrict__ beta,
    const float* __restrict__ w2, const float* __restrict__ b2,
    float* __restrict__ hout, float* __restrict__ aggr, int zero_aggr)
{
    int n = blockIdx.x * 256 + threadIdx.x;
    if (n >= NNODES) return;
    const float4* in4 = (const float4*)(h1 + (size_t)n * HID);
    const float4* s4p = (const float4*)bnacc;
    const float4* q4p = (const float4*)(bnacc + HID);
    const float4* g4p = (const float4*)gamma;
    const float4* b4p = (const float4*)beta;
    const float invN = 1.0f / (float)NNODES;
    float4 hrow[32];
#pragma unroll
    for (int k = 0; k < 32; ++k) {
        float4 v = in4[k], s = s4p[k], q = q4p[k], g = g4p[k], b = b4p[k];
        float mu, var, iv;
        mu = s.x * invN; var = fmaf(-mu, mu, q.x * invN); iv = rsqrtf(var + 1e-5f);
        hrow[k].x = leaky1(fmaf((v.x - mu) * iv, g.x, b.x));
        mu = s.y * invN; var = fmaf(-mu, mu, q.y * invN); iv = rsqrtf(var + 1e-5f);
        hrow[k].y = leaky1(fmaf((v.y - mu) * iv, g.y, b.y));
        mu = s.z * invN; var = fmaf(-mu, mu, q.z * invN); iv = rsqrtf(var + 1e-5f);
        hrow[k].z = leaky1(fmaf((v.z - mu) * iv, g.z, b.z));
        mu = s.w * invN; var = fmaf(-mu, mu, q.w * invN); iv = rsqrtf(var + 1e-5f);
        hrow[k].w = leaky1(fmaf((v.w - mu) * iv, g.w, b.w));
    }
    const float4* w4 = (const float4*)w2;
    float4* out4 = (float4*)(hout + (size_t)n * HID);
    for (int j = 0; j < HID; j += 4) {
        const float4* w0p = w4 + (size_t)(j + 0) * 32;
        const float4* w1p = w4 + (size_t)(j + 1) * 32;
        const float4* w2p = w4 + (size_t)(j + 2) * 32;
        const float4* w3p = w4 + (size_t)(j + 3) * 32;
        float a0 = b2[j + 0], a1 = b2[j + 1], a2 = b2[j + 2], a3 = b2[j + 3];
#pragma unroll
        for (int k = 0; k < 32; ++k) {
            float4 h4 = hrow[k];
            float4 q0 = w0p[k], q1 = w1p[k], q2 = w2p[k], q3 = w3p[k];
            a0 = fmaf(h4.x, q0.x, a0); a0 = fmaf(h4.y, q0.y, a0); a0 = fmaf(h4.z, q0.z, a0); a0 = fmaf(h4.w, q0.w, a0);
            a1 = fmaf(h4.x, q1.x, a1); a1 = fmaf(h4.y, q1.y, a1); a1 = fmaf(h4.z, q1.z, a1); a1 = fmaf(h4.w, q1.w, a1);
            a2 = fmaf(h4.x, q2.x, a2); a2 = fmaf(h4.y, q2.y, a2); a2 = fmaf(h4.z, q2.z, a2); a2 = fmaf(h4.w, q2.w, a2);
            a3 = fmaf(h4.x, q3.x, a3); a3 = fmaf(h4.y, q3.y, a3); a3 = fmaf(h4.z, q3.z, a3); a3 = fmaf(h4.w, q3.w, a3);
        }
        out4[j >> 2] = make_float4(leaky1(leaky1(a0)), leaky1(leaky1(a1)),
                                   leaky1(leaky1(a2)), leaky1(leaky1(a3)));
    }
    if (zero_aggr) {
        float4 z = make_float4(0.f, 0.f, 0.f, 0.f);
        float4* az = (float4*)(aggr + (size_t)n * HID);
#pragma unroll
        for (int k = 0; k < 32; ++k) az[k] = z;
    }
}

// ---------------- global mean pool (batch sorted): segmented accumulation ----------------
__global__ __launch_bounds__(256) void pool_kernel(
    const float* __restrict__ h, const int* __restrict__ batch,
    float* __restrict__ sums, float* __restrict__ cnt)
{
    int c = threadIdx.x & 127;
    int half = threadIdx.x >> 7;
    int base = blockIdx.x * 128 + half * 64;
    if (base >= NNODES) return;
    int end = base + 64; if (end > NNODES) end = NNODES;
    int g = batch[base];
    float acc = 0.0f, k = 0.0f;
    for (int n = base; n < end; ++n) {
        int gn = batch[n];
        if (gn != g) {
            atomicAdd(&sums[g * HID + c], acc);
            if (c == 0) atomicAdd(&cnt[g], k);
            acc = 0.0f; k = 0.0f; g = gn;
        }
        acc += h[(size_t)n * HID + c];
        k += 1.0f;
    }
    atomicAdd(&sums[g * HID + c], acc);
    if (c == 0) atomicAdd(&cnt[g], k);
}

// ---------------- reghead: pooled -> Lin(500) -> leaky -> Lin(1) ----------------
__global__ __launch_bounds__(512) void reghead_kernel(
    const float* __restrict__ sums, const float* __restrict__ cnt,
    const float* __restrict__ wr, const float* __restrict__ br,
    const float* __restrict__ we, const float* __restrict__ be,
    float* __restrict__ out)
{
    __shared__ float pool[8 * HID];
    __shared__ float red[8][8];
    int g0 = blockIdx.x * 8;
    for (int i = threadIdx.x; i < 8 * HID; i += 512) {
        int g = g0 + (i >> 7);
        float c = cnt[g]; c = fmaxf(c, 1.0f);
        pool[i] = sums[g * HID + (i & 127)] / c;
    }
    __syncthreads();
    int j = threadIdx.x;
    float p[8];
#pragma unroll
    for (int g = 0; g < 8; ++g) p[g] = 0.0f;
    if (j < RHD) {
        float accs[8];
        float bj = br[j];
#pragma unroll
        for (int g = 0; g < 8; ++g) accs[g] = bj;
        const float4* wr4 = (const float4*)(wr + (size_t)j * HID);
        const float4* pool4 = (const float4*)pool;
        for (int k = 0; k < 32; ++k) {
            float4 w = wr4[k];
#pragma unroll
            for (int g = 0; g < 8; ++g) {
                float4 pv = pool4[g * 32 + k];
                accs[g] = fmaf(w.x, pv.x, accs[g]);
                accs[g] = fmaf(w.y, pv.y, accs[g]);
                accs[g] = fmaf(w.z, pv.z, accs[g]);
                accs[g] = fmaf(w.w, pv.w, accs[g]);
            }
        }
        float wej = we[j];
#pragma unroll
        for (int g = 0; g < 8; ++g) p[g] = leaky1(accs[g]) * wej;
    }
    int lane = threadIdx.x & 63, wid = threadIdx.x >> 6;
#pragma unroll
    for (int g = 0; g < 8; ++g) {
        float v = p[g];
        v += __shfl_down(v, 32); v += __shfl_down(v, 16); v += __shfl_down(v, 8);
        v += __shfl_down(v, 4);  v += __shfl_down(v, 2);  v += __shfl_down(v, 1);
        if (lane == 0) red[g][wid] = v;
    }
    __syncthreads();
    if (threadIdx.x < 8) {
        float s = be[0];
#pragma unroll
        for (int w = 0; w < 8; ++w) s += red[threadIdx.x][w];
        out[g0 + threadIdx.x] = s;
    }
}

extern "C" void kernel_launch(void* const* d_in, const int* in_sizes, int n_in,
                              void* d_out, int out_size, void* d_ws, size_t ws_size,
                              hipStream_t stream)
{
    const float* x     = (const float*)d_in[0];
    const int*   ei    = (const int*)d_in[1];
    const int*   batch = (const int*)d_in[2];
    const float* ea    = (const float*)d_in[3];
    const float* ew0   = (const float*)d_in[4];
    const float* eb0   = (const float*)d_in[5];
    const float* w10   = (const float*)d_in[6];
    const float* b10   = (const float*)d_in[7];
    const float* g0v   = (const float*)d_in[8];
    const float* be0   = (const float*)d_in[9];
    const float* w20   = (const float*)d_in[10];
    const float* b20   = (const float*)d_in[11];
    const float* ewS   = (const float*)d_in[12];
    const float* ebS   = (const float*)d_in[13];
    const float* w1S   = (const float*)d_in[14];
    const float* b1S   = (const float*)d_in[15];
    const float* gS    = (const float*)d_in[16];
    const float* beS   = (const float*)d_in[17];
    const float* w2S   = (const float*)d_in[18];
    const float* b2S   = (const float*)d_in[19];
    const float* wr    = (const float*)d_in[20];
    const float* br    = (const float*)d_in[21];
    const float* we    = (const float*)d_in[22];
    const float* be_   = (const float*)d_in[23];

    float* ws   = (float*)d_ws;
    float* h    = ws;
    float* aggr = ws + (size_t)NNODES * HID;
    float* h1   = ws + 2ull * NNODES * HID;
    float* bn   = ws + 3ull * NNODES * HID;
    float* sums = bn + 256;
    float* cnt  = sums + NGRAPH * HID;
    float* out  = (float*)d_out;

    const int NB = (NNODES + 255) / 256;

    // ---- layer 0 ----
    hipMemsetAsync(aggr, 0, (size_t)NNODES * 2 * sizeof(float), stream);
    edge0_kernel<<<(NEDGES + 255) / 256, 256, 0, stream>>>(x, ei, ea, ew0, eb0, aggr);
    gemm1_l0_kernel<<<NB, 256, 0, stream>>>(x, aggr, w10, b10, h1);
    hipMemsetAsync(bn, 0, 256 * sizeof(float), stream);
    bn_stats_kernel<<<NB, 256, 0, stream>>>(h1, bn);
    gemm2_kernel<<<NB, 256, 0, stream>>>(h1, bn, g0v, be0, w20, b20, h, aggr, 1);

    // ---- hidden layers ----
    for (int i = 0; i < 3; ++i) {
        edge_kernel<<<NEDGES / 4, 256, 0, stream>>>(h, ei, ea,
            ewS + (size_t)i * HID * 7, ebS + (size_t)i * HID, aggr);
        gemm1_kernel<<<NB, 256, 0, stream>>>(h, aggr,
            w1S + (size_t)i * HID * HID, b1S + (size_t)i * HID, h1);
        hipMemsetAsync(bn, 0, 256 * sizeof(float), stream);
        bn_stats_kernel<<<NB, 256, 0, stream>>>(h1, bn);
        gemm2_kernel<<<NB, 256, 0, stream>>>(h1, bn,
            gS + (size_t)i * HID, beS + (size_t)i * HID,
            w2S + (size_t)i * HID * HID, b2S + (size_t)i * HID, h, aggr, (i < 2) ? 1 : 0);
    }

    // ---- pooling + reghead ----
    hipMemsetAsync(sums, 0, (size_t)(NGRAPH * HID + NGRAPH) * sizeof(float), stream);
    pool_kernel<<<(NNODES + 127) / 128, 256, 0, stream>>>(h, batch, sums, cnt);
    reghead_kernel<<<NGRAPH / 8, 512, 0, stream>>>(sums, cnt, wr, br, we, be_, out);
}